// Round 1
// baseline (419.713 us; speedup 1.0000x reference)
//
#include <hip/hip_runtime.h>

// ---------------------------------------------------------------------------
// VelocityEncoder fused pipeline for MI355X (gfx950)
//   stage1: per-row exact top-4-smallest (tie-break by index, == jax top_k),
//           neighbor gather, combined@W1+b1, ReLU, LayerNorm,
//           write h as bf16 hi/lo planes in K-tiled layout [kt][row][32]
//   w2split: W2 (fp32 256x256) -> bf16 hi/lo, transposed+K-tiled [kt][n][32]
//   stage2: out = h @ W2 + b2 via bf16x3 (hi*hi + hi*lo + lo*hi) MFMA GEMM
// ---------------------------------------------------------------------------

typedef __bf16 bf16x8 __attribute__((ext_vector_type(8)));
typedef unsigned short u16x8 __attribute__((ext_vector_type(8)));
typedef float f32x16 __attribute__((ext_vector_type(16)));

static __device__ __forceinline__ unsigned short f2bf(float x) {
    unsigned u = __float_as_uint(x);
    u += 0x7FFFu + ((u >> 16) & 1u);   // round-to-nearest-even
    return (unsigned short)(u >> 16);
}
static __device__ __forceinline__ float bf2f(unsigned short u) {
    return __uint_as_float(((unsigned)u) << 16);
}

#define UMIN64(a, b) ((a) < (b) ? (a) : (b))
#define CE64(x, y)                                                         \
    do {                                                                   \
        unsigned long long _mn = (x) < (y) ? (x) : (y);                    \
        unsigned long long _mx = (x) < (y) ? (y) : (x);                    \
        (x) = _mn; (y) = _mx;                                              \
    } while (0)

// ---------------------------------------------------------------------------
// stage 1: one wave per row (4 rows per 256-thread block), wave-local only.
// ---------------------------------------------------------------------------
__global__ __launch_bounds__(256) void stage1_kernel(
    const float* __restrict__ vel, const float* __restrict__ dist,
    const float* __restrict__ W1, const float* __restrict__ b1,
    const float* __restrict__ gammav, const float* __restrict__ betav,
    unsigned short* __restrict__ h_hi, unsigned short* __restrict__ h_lo)
{
    const int lane = threadIdx.x & 63;
    const int r = blockIdx.x * 4 + (threadIdx.x >> 6);   // row in [0, 65536)
    const float* drow = dist + (size_t)r * 1024;

    // coalesced: instr j loads float4 at drow[j*256 + lane*4]
    float v[16];
    {
        #pragma unroll
        for (int j = 0; j < 4; ++j) {
            float4 t = *(const float4*)(drow + j * 256 + lane * 4);
            v[j * 4 + 0] = t.x; v[j * 4 + 1] = t.y;
            v[j * 4 + 2] = t.z; v[j * 4 + 3] = t.w;
        }
    }

    // per-lane sorted (ascending) top-4 of 16, 64-bit keys (bits<<32 | idx)
    unsigned long long c0 = ~0ull, c1 = ~0ull, c2 = ~0ull, c3 = ~0ull;
    #pragma unroll
    for (int j = 0; j < 4; ++j) {
        #pragma unroll
        for (int c = 0; c < 4; ++c) {
            const unsigned idx = (unsigned)(j * 256 + lane * 4 + c);
            const unsigned long long k =
                ((unsigned long long)__float_as_uint(v[j * 4 + c]) << 32) | idx;
            if (k < c3) {
                unsigned long long t1 = c0 < k ? k : c0;  c0 = UMIN64(c0, k);
                unsigned long long t2 = c1 < t1 ? t1 : c1; c1 = UMIN64(c1, t1);
                unsigned long long t3 = c2 < t2 ? t2 : c2; c2 = UMIN64(c2, t2);
                c3 = UMIN64(c3, t3);
            }
        }
    }

    // 6-level bitonic top-4 allreduce across 64 lanes
    #pragma unroll
    for (int s = 1; s < 64; s <<= 1) {
        unsigned long long p0 = __shfl_xor(c0, s);
        unsigned long long p1 = __shfl_xor(c1, s);
        unsigned long long p2 = __shfl_xor(c2, s);
        unsigned long long p3 = __shfl_xor(c3, s);
        unsigned long long l0 = UMIN64(c0, p3);
        unsigned long long l1 = UMIN64(c1, p2);
        unsigned long long l2 = UMIN64(c2, p1);
        unsigned long long l3 = UMIN64(c3, p0);
        CE64(l0, l2); CE64(l1, l3); CE64(l0, l1); CE64(l2, l3);
        c0 = l0; c1 = l1; c2 = l2; c3 = l3;
    }
    // neighbors = 2nd..4th smallest (reference drops idx[...,0])
    const unsigned i1 = (unsigned)c1, i2 = (unsigned)c2, i3 = (unsigned)c3;

    const int b_ = r >> 10;
    const float* va = vel + (size_t)r * 3;
    const size_t vb = (size_t)(b_ << 10) * 3;
    const float* n1 = vel + vb + (size_t)i1 * 3;
    const float* n2 = vel + vb + (size_t)i2 * 3;
    const float* n3 = vel + vb + (size_t)i3 * 3;
    const float ax = va[0], ay = va[1], az = va[2];
    const float mx = (n1[0] + n2[0] + n3[0]) * (1.0f / 3.0f);
    const float my = (n1[1] + n2[1] + n3[1]) * (1.0f / 3.0f);
    const float mz = (n1[2] + n2[2] + n3[2]) * (1.0f / 3.0f);
    const float cb[6] = {ax, ay, az, ax - mx, ay - my, az - mz};

    // h[e] for e = lane*4 .. lane*4+3
    const int e0 = lane * 4;
    float4 bb = *(const float4*)(b1 + e0);
    float h0 = bb.x, h1 = bb.y, h2 = bb.z, h3 = bb.w;
    #pragma unroll
    for (int f = 0; f < 6; ++f) {
        float4 w = *(const float4*)(W1 + f * 256 + e0);
        h0 = fmaf(cb[f], w.x, h0); h1 = fmaf(cb[f], w.y, h1);
        h2 = fmaf(cb[f], w.z, h2); h3 = fmaf(cb[f], w.w, h3);
    }
    h0 = fmaxf(h0, 0.f); h1 = fmaxf(h1, 0.f);
    h2 = fmaxf(h2, 0.f); h3 = fmaxf(h3, 0.f);

    // LayerNorm over 256 channels (wave reduce)
    float s = h0 + h1 + h2 + h3;
    float s2 = h0 * h0 + h1 * h1 + h2 * h2 + h3 * h3;
    #pragma unroll
    for (int o = 32; o; o >>= 1) {
        s += __shfl_xor(s, o);
        s2 += __shfl_xor(s2, o);
    }
    const float mu = s * (1.0f / 256.0f);
    const float var = s2 * (1.0f / 256.0f) - mu * mu;
    const float inv = rsqrtf(var + 1e-5f);
    float4 g = *(const float4*)(gammav + e0);
    float4 be = *(const float4*)(betav + e0);
    const float y0 = (h0 - mu) * inv * g.x + be.x;
    const float y1 = (h1 - mu) * inv * g.y + be.y;
    const float y2 = (h2 - mu) * inv * g.z + be.z;
    const float y3 = (h3 - mu) * inv * g.w + be.w;

    ushort4 hv, lv;
    hv.x = f2bf(y0); lv.x = f2bf(y0 - bf2f(hv.x));
    hv.y = f2bf(y1); lv.y = f2bf(y1 - bf2f(hv.y));
    hv.z = f2bf(y2); lv.z = f2bf(y2 - bf2f(hv.z));
    hv.w = f2bf(y3); lv.w = f2bf(y3 - bf2f(hv.w));

    // K-tiled layout: [kt = e>>5][row][e&31]; e0 = lane*4
    const size_t hoff = ((size_t)(lane >> 3) * 65536 + (size_t)r) * 32 + (lane & 7) * 4;
    *(ushort4*)(h_hi + hoff) = hv;
    *(ushort4*)(h_lo + hoff) = lv;
}

// ---------------------------------------------------------------------------
// W2 split: fp32 [k][n] -> bf16 hi/lo, layout [kt=k>>5][n][k&31]
// ---------------------------------------------------------------------------
__global__ __launch_bounds__(256) void w2split_kernel(
    const float* __restrict__ W2,
    unsigned short* __restrict__ bt_hi, unsigned short* __restrict__ bt_lo)
{
    const int k = blockIdx.x;    // 0..255
    const int n = threadIdx.x;   // 0..255
    const float w = W2[k * 256 + n];
    const unsigned short hi = f2bf(w);
    const unsigned short lo = f2bf(w - bf2f(hi));
    const size_t off = (size_t)(k >> 5) * 8192 + (size_t)n * 32 + (k & 31);
    bt_hi[off] = hi;
    bt_lo[off] = lo;
}

// ---------------------------------------------------------------------------
// stage 2: out(65536x256) = h @ W2 + b2, bf16x3 MFMA (32x32x16)
// block: 256 thr = 4 waves, BM=64, BN=256 (wave n-quadrant), BK=32, 8 k-iters
// LDS pair-row layout + XOR swizzle: row pair -> 128B LDS row of 8 16B slots,
// slot' = ((row&1)*4 | q) ^ ((row>>1)&7)
// ---------------------------------------------------------------------------
#define MFMA(acc, a, b) \
    (acc) = __builtin_amdgcn_mfma_f32_32x32x16_bf16((a), (b), (acc), 0, 0, 0)

__global__ __launch_bounds__(256, 4) void stage2_kernel(
    const unsigned short* __restrict__ h_hi, const unsigned short* __restrict__ h_lo,
    const unsigned short* __restrict__ bt_hi, const unsigned short* __restrict__ bt_lo,
    const float* __restrict__ b2, float* __restrict__ out)
{
    __shared__ __align__(16) unsigned short As[2][32][64];    // 16 KiB
    __shared__ __align__(16) unsigned short Bs[2][128][64];   // 32 KiB

    const int tid = threadIdx.x;
    const int lane = tid & 63;
    const int wid = tid >> 6;        // n-quadrant 0..3
    const int l31 = lane & 31;
    const int lh = lane >> 5;
    const size_t rowM0 = (size_t)blockIdx.x * 64;

    unsigned short* Asw = &As[0][0][0];   // plane stride 2048 ushorts
    unsigned short* Bsw = &Bs[0][0][0];   // plane stride 8192 ushorts

    f32x16 acc00, acc01, acc10, acc11;
    #pragma unroll
    for (int i = 0; i < 16; ++i) { acc00[i] = 0.f; acc01[i] = 0.f; acc10[i] = 0.f; acc11[i] = 0.f; }

    // --- staging maps ---
    const int arow = tid >> 2, aq = tid & 3;
    const size_t a_src_base = (rowM0 + (size_t)arow) * 32 + aq * 8;   // + kt*65536*32
    const int a_lds = (arow >> 1) * 64 + (((((arow & 1) << 2) | aq) ^ ((arow >> 1) & 7)) << 3);

    const int bq = tid & 3, bnb = tid >> 2;
    const int bs_ = ((((bnb & 1) << 2) | bq) ^ ((bnb >> 1) & 7));
    const int b_lds_base = (bnb >> 1) * 64 + (bs_ << 3);

    // --- fragment read maps ---
    const int arow0 = l31, arow1 = 32 + l31;
    const int aB0 = (arow0 >> 1) * 64, aK0 = ((arow0 & 1) << 2) ^ ((arow0 >> 1) & 7);
    const int aB1 = (arow1 >> 1) * 64, aK1 = ((arow1 & 1) << 2) ^ ((arow1 >> 1) & 7);
    const int bn0 = wid * 64 + l31, bn1 = bn0 + 32;
    const int bB0 = (bn0 >> 1) * 64, bK0 = ((bn0 & 1) << 2) ^ ((bn0 >> 1) & 7);
    const int bB1 = (bn1 >> 1) * 64, bK1 = ((bn1 & 1) << 2) ^ ((bn1 >> 1) & 7);

    #define LDF(base, off) __builtin_bit_cast(bf16x8, *(const u16x8*)((base) + (off)))

    for (int kt = 0; kt < 8; ++kt) {
        // A loads issued before barrier: in flight during barrier wait
        const size_t asrc = a_src_base + (size_t)kt * (65536ull * 32ull);
        uint4 va0 = *(const uint4*)(h_hi + asrc);
        uint4 va1 = *(const uint4*)(h_lo + asrc);
        __syncthreads();   // prior iteration's LDS reads complete
        *(uint4*)(Asw + a_lds) = va0;
        *(uint4*)(Asw + 2048 + a_lds) = va1;
        #pragma unroll
        for (int pass = 0; pass < 4; ++pass) {
            const size_t boff = (size_t)kt * 8192 + (size_t)(pass * 64 + bnb) * 32 + bq * 8;
            uint4 vb0 = *(const uint4*)(bt_hi + boff);
            uint4 vb1 = *(const uint4*)(bt_lo + boff);
            const int lo_ = b_lds_base + pass * 2048;
            *(uint4*)(Bsw + lo_) = vb0;
            *(uint4*)(Bsw + 8192 + lo_) = vb1;
        }
        __syncthreads();

        #pragma unroll
        for (int ks = 0; ks < 2; ++ks) {
            const int slot = ks * 2 + lh;
            bf16x8 a0h = LDF(Asw,        aB0 + ((aK0 ^ slot) << 3));
            bf16x8 a0l = LDF(Asw + 2048, aB0 + ((aK0 ^ slot) << 3));
            bf16x8 a1h = LDF(Asw,        aB1 + ((aK1 ^ slot) << 3));
            bf16x8 a1l = LDF(Asw + 2048, aB1 + ((aK1 ^ slot) << 3));
            bf16x8 b0h = LDF(Bsw,        bB0 + ((bK0 ^ slot) << 3));
            bf16x8 b0l = LDF(Bsw + 8192, bB0 + ((bK0 ^ slot) << 3));
            bf16x8 b1h = LDF(Bsw,        bB1 + ((bK1 ^ slot) << 3));
            bf16x8 b1l = LDF(Bsw + 8192, bB1 + ((bK1 ^ slot) << 3));
            MFMA(acc00, a0h, b0h); MFMA(acc00, a0h, b0l); MFMA(acc00, a0l, b0h);
            MFMA(acc01, a0h, b1h); MFMA(acc01, a0h, b1l); MFMA(acc01, a0l, b1h);
            MFMA(acc10, a1h, b0h); MFMA(acc10, a1h, b0l); MFMA(acc10, a1l, b0h);
            MFMA(acc11, a1h, b1h); MFMA(acc11, a1h, b1l); MFMA(acc11, a1l, b1h);
        }
    }

    // epilogue: C/D layout col = lane&31, row = (reg&3) + 8*(reg>>2) + 4*(lane>>5)
    const int col0 = wid * 64 + l31;
    const int col1 = col0 + 32;
    const float bias0 = b2[col0];
    const float bias1 = b2[col1];
    #pragma unroll
    for (int q2 = 0; q2 < 4; ++q2) {
        #pragma unroll
        for (int j = 0; j < 4; ++j) {
            const int reg = q2 * 4 + j;
            const size_t row0 = rowM0 + (size_t)(j + 8 * q2 + 4 * lh);
            out[row0 * 256 + col0] = acc00[reg] + bias0;
            out[row0 * 256 + col1] = acc01[reg] + bias1;
            out[(row0 + 32) * 256 + col0] = acc10[reg] + bias0;
            out[(row0 + 32) * 256 + col1] = acc11[reg] + bias1;
        }
    }
}

// ---------------------------------------------------------------------------
extern "C" void kernel_launch(void* const* d_in, const int* in_sizes, int n_in,
                              void* d_out, int out_size, void* d_ws, size_t ws_size,
                              hipStream_t stream)
{
    const float* vel   = (const float*)d_in[0];
    const float* dist  = (const float*)d_in[1];
    const float* W1    = (const float*)d_in[2];
    const float* b1    = (const float*)d_in[3];
    const float* gam   = (const float*)d_in[4];
    const float* bet   = (const float*)d_in[5];
    const float* W2    = (const float*)d_in[6];
    const float* b2    = (const float*)d_in[7];
    float* out = (float*)d_out;

    // workspace layout (needs ~64.25 MiB)
    unsigned short* h_hi  = (unsigned short*)d_ws;
    unsigned short* h_lo  = h_hi + 16777216ull;   // 65536*256
    unsigned short* bt_hi = h_lo + 16777216ull;
    unsigned short* bt_lo = bt_hi + 65536ull;

    w2split_kernel<<<256, 256, 0, stream>>>(W2, bt_hi, bt_lo);
    stage1_kernel<<<16384, 256, 0, stream>>>(vel, dist, W1, b1, gam, bet, h_hi, h_lo);
    stage2_kernel<<<1024, 256, 0, stream>>>(h_hi, h_lo, bt_hi, bt_lo, b2, out);
}